// Round 1
// baseline (27.930 us; speedup 1.0000x reference)
//
#include <hip/hip_runtime.h>

// Problem dims (fixed by setup_inputs): B=8, n=128, d=512, h=1024
constexpr int Bn = 8, Nn = 128, Dd = 512, Hh = 1024;
constexpr int Ff = 2 * Dd;  // 1024 feature dim

// ---------------------------------------------------------------------------
// Kernel 1: v[f] = dot(W1[f, :], W2)  for f in [0, Ff);  v[Ff] = dot(b1, W2) + b2
// One wave (64 lanes) per row; float4 loads; shuffle reduce.
// ---------------------------------------------------------------------------
__global__ __launch_bounds__(256) void k_wv(const float* __restrict__ W1,
                                            const float* __restrict__ b1,
                                            const float* __restrict__ W2,
                                            const float* __restrict__ b2,
                                            float* __restrict__ v) {
    const int wave = (int)((blockIdx.x * 256u + threadIdx.x) >> 6);
    const int lane = threadIdx.x & 63;
    const float* row;
    if (wave < Ff)       row = W1 + (size_t)wave * Hh;
    else if (wave == Ff) row = b1;
    else return;

    const float4* r4 = (const float4*)row;
    const float4* w4 = (const float4*)W2;
    float p = 0.f;
#pragma unroll
    for (int q = 0; q < Hh / 256; ++q) {   // Hh/4 float4s per row, 64 lanes
        float4 x = r4[lane + 64 * q];
        float4 y = w4[lane + 64 * q];
        p = fmaf(x.x, y.x, p);
        p = fmaf(x.y, y.y, p);
        p = fmaf(x.z, y.z, p);
        p = fmaf(x.w, y.w, p);
    }
#pragma unroll
    for (int off = 32; off > 0; off >>= 1) p += __shfl_down(p, off);
    if (lane == 0) v[wave] = (wave == Ff) ? (p + b2[0]) : p;
}

// ---------------------------------------------------------------------------
// Kernel 2: scores[b,i,j] = sum_k a[b,i,k]*v1[k]*b[b,j,k] + alpha_i - beta_j + c
// 32x32 output tile per block, 256 threads, 2x2 micro-tile per thread.
// alpha/beta accumulated inline in the same K pass.
// ---------------------------------------------------------------------------
constexpr int TI = 32, TJ = 32, KC = 128, PADF = 4;

__global__ __launch_bounds__(256) void k_scores(const float* __restrict__ A,
                                                const float* __restrict__ Bm,
                                                const float* __restrict__ v,
                                                float* __restrict__ out) {
    __shared__ float a_s[TI][KC + PADF];
    __shared__ float b_s[TJ][KC + PADF];
    __shared__ float v1_s[KC];
    __shared__ float v2_s[KC];

    const int batch = blockIdx.z;
    const int brow = blockIdx.y * TI;
    const int bcol = blockIdx.x * TJ;
    const int tid = threadIdx.x;
    const int r = tid >> 4, c = tid & 15;

    const float* Ab = A + ((size_t)batch * Nn + brow) * Dd;
    const float* Bb = Bm + ((size_t)batch * Nn + bcol) * Dd;

    float acc00 = 0.f, acc01 = 0.f, acc10 = 0.f, acc11 = 0.f;
    float al0 = 0.f, al1 = 0.f, be0 = 0.f, be1 = 0.f;

    const int srow = tid >> 3, sc0 = tid & 7;  // staging: 8 threads per row

    for (int kc = 0; kc < Dd; kc += KC) {
        // stage a/b tiles: 32 rows x 128 floats (= 32 float4 per row)
        const float4* ga = (const float4*)(Ab + (size_t)srow * Dd + kc);
        const float4* gb = (const float4*)(Bb + (size_t)srow * Dd + kc);
#pragma unroll
        for (int q = 0; q < 4; ++q) {
            const int cc = sc0 + 8 * q;
            *(float4*)&a_s[srow][cc * 4] = ga[cc];
            *(float4*)&b_s[srow][cc * 4] = gb[cc];
        }
        if (tid < KC) v1_s[tid] = v[kc + tid];
        else          v2_s[tid - KC] = v[Dd + kc + (tid - KC)];
        __syncthreads();

#pragma unroll 8
        for (int k = 0; k < KC; ++k) {
            const float w1 = v1_s[k], w2 = v2_s[k];
            const float a0 = a_s[2 * r][k],     a1 = a_s[2 * r + 1][k];
            const float b0 = b_s[2 * c][k],     b1 = b_s[2 * c + 1][k];
            const float p0 = a0 * w1, p1 = a1 * w1;
            acc00 = fmaf(p0, b0, acc00);
            acc01 = fmaf(p0, b1, acc01);
            acc10 = fmaf(p1, b0, acc10);
            acc11 = fmaf(p1, b1, acc11);
            al0 = fmaf(a0, w2, al0);
            al1 = fmaf(a1, w2, al1);
            be0 = fmaf(b0, w2, be0);
            be1 = fmaf(b1, w2, be1);
        }
        __syncthreads();
    }

    const float cterm = v[Ff];
    const int i0 = brow + 2 * r, j0 = bcol + 2 * c;
    float* o = out + ((size_t)batch * Nn + i0) * Nn + j0;
    o[0]      = acc00 + al0 - be0 + cterm;
    o[1]      = acc01 + al0 - be1 + cterm;
    o[Nn]     = acc10 + al1 - be0 + cterm;
    o[Nn + 1] = acc11 + al1 - be1 + cterm;
}

extern "C" void kernel_launch(void* const* d_in, const int* in_sizes, int n_in,
                              void* d_out, int out_size, void* d_ws, size_t ws_size,
                              hipStream_t stream) {
    const float* a  = (const float*)d_in[0];
    const float* b  = (const float*)d_in[1];
    const float* W1 = (const float*)d_in[2];
    const float* b1 = (const float*)d_in[3];
    const float* W2 = (const float*)d_in[4];
    const float* b2 = (const float*)d_in[5];
    float* out = (float*)d_out;
    float* v   = (float*)d_ws;  // Ff + 1 floats

    const int waves1 = Ff + 1;                 // 1024 rows + c
    const int blocks1 = (waves1 + 3) / 4;      // 4 waves per block
    k_wv<<<blocks1, 256, 0, stream>>>(W1, b1, W2, b2, v);

    dim3 g2(Nn / TJ, Nn / TI, Bn);             // (4, 4, 8)
    k_scores<<<g2, 256, 0, stream>>>(a, b, v, out);
}

// Round 2
// 21.172 us; speedup vs baseline: 1.3192x; 1.3192x over previous
//
#include <hip/hip_runtime.h>

// Problem dims (fixed by setup_inputs): B=8, n=128, d=512, h=1024
constexpr int Bn = 8, Nn = 128, Dd = 512, Hh = 1024;
constexpr int Ff = 2 * Dd;  // 1024

// ---------------------------------------------------------------------------
// Kernel 1: v[f] = dot(W1[f,:], W2) for f < Ff; v[Ff] = dot(b1, W2) + b2
// One wave per row, float4 loads, shuffle reduce.
// ---------------------------------------------------------------------------
__global__ __launch_bounds__(256) void k_wv(const float* __restrict__ W1,
                                            const float* __restrict__ b1,
                                            const float* __restrict__ W2,
                                            const float* __restrict__ b2,
                                            float* __restrict__ v) {
    const int wave = (int)((blockIdx.x * 256u + threadIdx.x) >> 6);
    const int lane = threadIdx.x & 63;
    const float* row;
    if (wave < Ff)       row = W1 + (size_t)wave * Hh;
    else if (wave == Ff) row = b1;
    else return;

    const float4* r4 = (const float4*)row;
    const float4* w4 = (const float4*)W2;
    float p = 0.f;
#pragma unroll
    for (int q = 0; q < Hh / 256; ++q) {
        float4 x = r4[lane + 64 * q];
        float4 y = w4[lane + 64 * q];
        p = fmaf(x.x, y.x, p);
        p = fmaf(x.y, y.y, p);
        p = fmaf(x.z, y.z, p);
        p = fmaf(x.w, y.w, p);
    }
#pragma unroll
    for (int off = 32; off; off >>= 1) p += __shfl_down(p, off);
    if (lane == 0) v[wave] = (wave == Ff) ? (p + b2[0]) : p;
}

// ---------------------------------------------------------------------------
// Kernel 2: scores[b,i,j] = sum_k aw[i,k]*b[j,k] + alpha_i - beta_j + c
//   aw = a * v1 computed at staging; alpha/beta partials accumulated during
//   staging from registers; inner loop = pure float4 FMA.
// Tile 32(i) x 16(j), 256 threads, micro 2x1. Grid (8,4,8) = 256 blocks.
// ---------------------------------------------------------------------------
constexpr int TI = 32, TJ = 16, KC = 128, SP = KC + 4;  // stride 132: <=2-way banks

__global__ __launch_bounds__(256) void k_scores(const float* __restrict__ A,
                                                const float* __restrict__ Bm,
                                                const float* __restrict__ vg,
                                                float* __restrict__ out) {
    __shared__ float aw_s[TI][SP];
    __shared__ float b_s[TJ][SP];
    __shared__ float v_s[Ff + 4];
    __shared__ float al_s[TI];
    __shared__ float be_s[TJ];

    const int batch = blockIdx.z;
    const int brow  = blockIdx.y * TI;
    const int bcol  = blockIdx.x * TJ;
    const int tid   = threadIdx.x;

    // stage the whole v vector (1025 floats) once
    {
        float4 t = ((const float4*)vg)[tid];
        *(float4*)&v_s[tid * 4] = t;
        if (tid == 0) v_s[Ff] = vg[Ff];
    }
    __syncthreads();

    const int sra = tid >> 3, sca = tid & 7;    // a-staging: 32 rows x 8 thr
    const int srb = tid >> 4, scb = tid & 15;   // b-staging: 16 rows x 16 thr
    const int r   = tid >> 4, c   = tid & 15;   // compute: 16 row-pairs x 16 cols

    const float* ga = A  + (size_t)(batch * Nn + brow + sra) * Dd;
    const float* gb = Bm + (size_t)(batch * Nn + bcol + srb) * Dd;

    float acc0 = 0.f, acc1 = 0.f, alp = 0.f, bep = 0.f;

    for (int kc = 0; kc < Dd; kc += KC) {
        // stage aw = a*v1, accumulate alpha partial (a . v2)
#pragma unroll
        for (int q = 0; q < 4; ++q) {
            const int cc = sca + 8 * q;  // float4 col in chunk [0,32)
            float4 av  = ((const float4*)(ga + kc))[cc];
            float4 w1v = *(const float4*)&v_s[kc + 4 * cc];
            float4 w2v = *(const float4*)&v_s[Dd + kc + 4 * cc];
            alp = fmaf(av.x, w2v.x, alp); alp = fmaf(av.y, w2v.y, alp);
            alp = fmaf(av.z, w2v.z, alp); alp = fmaf(av.w, w2v.w, alp);
            float4 w;
            w.x = av.x * w1v.x; w.y = av.y * w1v.y;
            w.z = av.z * w1v.z; w.w = av.w * w1v.w;
            *(float4*)&aw_s[sra][4 * cc] = w;
        }
        // stage b, accumulate beta partial (b . v2)
#pragma unroll
        for (int q = 0; q < 2; ++q) {
            const int cc = scb + 16 * q;
            float4 bv  = ((const float4*)(gb + kc))[cc];
            float4 w2v = *(const float4*)&v_s[Dd + kc + 4 * cc];
            bep = fmaf(bv.x, w2v.x, bep); bep = fmaf(bv.y, w2v.y, bep);
            bep = fmaf(bv.z, w2v.z, bep); bep = fmaf(bv.w, w2v.w, bep);
            *(float4*)&b_s[srb][4 * cc] = bv;
        }
        __syncthreads();

#pragma unroll 8
        for (int k4 = 0; k4 < KC / 4; ++k4) {
            float4 w0 = *(const float4*)&aw_s[2 * r][4 * k4];
            float4 w1 = *(const float4*)&aw_s[2 * r + 1][4 * k4];
            float4 bv = *(const float4*)&b_s[c][4 * k4];
            acc0 = fmaf(w0.x, bv.x, acc0); acc0 = fmaf(w0.y, bv.y, acc0);
            acc0 = fmaf(w0.z, bv.z, acc0); acc0 = fmaf(w0.w, bv.w, acc0);
            acc1 = fmaf(w1.x, bv.x, acc1); acc1 = fmaf(w1.y, bv.y, acc1);
            acc1 = fmaf(w1.z, bv.z, acc1); acc1 = fmaf(w1.w, bv.w, acc1);
        }
        __syncthreads();
    }

    // alpha: 8 consecutive lanes share a row
#pragma unroll
    for (int off = 4; off; off >>= 1) alp += __shfl_xor(alp, off);
    if (sca == 0) al_s[sra] = alp;
    // beta: 16 consecutive lanes share a row
#pragma unroll
    for (int off = 8; off; off >>= 1) bep += __shfl_xor(bep, off);
    if (scb == 0) be_s[srb] = bep;
    __syncthreads();

    const float ct = v_s[Ff];
    float* o = out + (size_t)(batch * Nn + brow + 2 * r) * Nn + bcol + c;
    o[0]  = acc0 + al_s[2 * r]     - be_s[c] + ct;
    o[Nn] = acc1 + al_s[2 * r + 1] - be_s[c] + ct;
}

extern "C" void kernel_launch(void* const* d_in, const int* in_sizes, int n_in,
                              void* d_out, int out_size, void* d_ws, size_t ws_size,
                              hipStream_t stream) {
    const float* a  = (const float*)d_in[0];
    const float* b  = (const float*)d_in[1];
    const float* W1 = (const float*)d_in[2];
    const float* b1 = (const float*)d_in[3];
    const float* W2 = (const float*)d_in[4];
    const float* b2 = (const float*)d_in[5];
    float* out = (float*)d_out;
    float* v   = (float*)d_ws;  // Ff + 1 floats

    const int blocks1 = (Ff + 1 + 3) / 4;      // 4 waves per block
    k_wv<<<blocks1, 256, 0, stream>>>(W1, b1, W2, b2, v);

    dim3 g2(Nn / TJ, Nn / TI, Bn);             // (8, 4, 8) = 256 blocks
    k_scores<<<g2, 256, 0, stream>>>(a, b, v, out);
}

// Round 3
// 18.777 us; speedup vs baseline: 1.4875x; 1.1275x over previous
//
#include <hip/hip_runtime.h>

// Problem dims (fixed): B=8, n=128, d=512, h=1024
constexpr int Bn = 8, Nn = 128, Dd = 512, Hh = 1024;
constexpr int Ff = 2 * Dd;            // 1024
constexpr int KS = 8, KCH = Dd / KS;  // K-split 8, chunk 64

// ws layout (float offsets):
//   v     [0, 1025)
//   alpha [AOFF + (s*Bn+b)*Nn + i]   8*8*128
//   beta  [BOFF + (s*Bn+b)*Nn + j]   8*8*128
//   part  [POFF + ((s*Bn+b)*Nn+i)*Nn + j]  8*8*128*128
constexpr int AOFF = 2048, BOFF = 10240, POFF = 32768;

// ---------------------------------------------------------------------------
// Kernel 1: v[f] = dot(W1[f,:], W2);  v[Ff] = dot(b1, W2) + b2
// ---------------------------------------------------------------------------
__global__ __launch_bounds__(256) void k_wv(const float* __restrict__ W1,
                                            const float* __restrict__ b1,
                                            const float* __restrict__ W2,
                                            const float* __restrict__ b2,
                                            float* __restrict__ v) {
    const int wave = (int)((blockIdx.x * 256u + threadIdx.x) >> 6);
    const int lane = threadIdx.x & 63;
    const float* row;
    if (wave < Ff)       row = W1 + (size_t)wave * Hh;
    else if (wave == Ff) row = b1;
    else return;

    const float4* r4 = (const float4*)row;
    const float4* w4 = (const float4*)W2;
    float p = 0.f;
#pragma unroll
    for (int q = 0; q < Hh / 256; ++q) {
        float4 x = r4[lane + 64 * q];
        float4 y = w4[lane + 64 * q];
        p = fmaf(x.x, y.x, p);
        p = fmaf(x.y, y.y, p);
        p = fmaf(x.z, y.z, p);
        p = fmaf(x.w, y.w, p);
    }
#pragma unroll
    for (int off = 32; off; off >>= 1) p += __shfl_down(p, off);
    if (lane == 0) v[wave] = (wave == Ff) ? (p + b2[0]) : p;
}

// ---------------------------------------------------------------------------
// Kernel 2: bilinear partials, K-split. Tile 64x64, 4x4 micro, k-major LDS.
// Grid (4 tiles, 8 batch, 8 ksplit) = 256 blocks x 256 threads.
// ---------------------------------------------------------------------------
__global__ __launch_bounds__(256) void k_bil(const float* __restrict__ A,
                                             const float* __restrict__ Bm,
                                             float* __restrict__ ws) {
    __shared__ float aw_t[KCH][64];   // k-major: aw_t[k][row] = a*v1
    __shared__ float b_t[KCH][64];    // b_t[k][col]
    __shared__ float ared[4][64];
    __shared__ float bred[4][64];

    const int it = blockIdx.x >> 1, jt = blockIdx.x & 1;
    const int batch = blockIdx.y, s = blockIdx.z;
    const int t = threadIdx.x;
    const int K0 = s * KCH;

    // ---- staging: row = lane, 4 float4 chunks per thread; transpose to LDS
    const int row = t & 63, c0 = t >> 6;
    const float* arow = A  + (size_t)(batch * Nn + it * 64 + row) * Dd + K0;
    const float* brow = Bm + (size_t)(batch * Nn + jt * 64 + row) * Dd + K0;
    const float4* w1p = (const float4*)(ws + K0);        // v1 chunk (global, L2-hot)
    const float4* w2p = (const float4*)(ws + Dd + K0);   // v2 chunk

    float alp = 0.f, bep = 0.f;
#pragma unroll
    for (int q = 0; q < 4; ++q) {
        const int f4 = c0 + 4 * q;              // 0..15
        float4 av = ((const float4*)arow)[f4];
        float4 bv = ((const float4*)brow)[f4];
        float4 w1 = w1p[f4];
        float4 w2 = w2p[f4];
        alp = fmaf(av.x, w2.x, alp); alp = fmaf(av.y, w2.y, alp);
        alp = fmaf(av.z, w2.z, alp); alp = fmaf(av.w, w2.w, alp);
        bep = fmaf(bv.x, w2.x, bep); bep = fmaf(bv.y, w2.y, bep);
        bep = fmaf(bv.z, w2.z, bep); bep = fmaf(bv.w, w2.w, bep);
        const int k = 4 * f4;
        aw_t[k + 0][row] = av.x * w1.x;        // all lanes same k, rows 0..63:
        aw_t[k + 1][row] = av.y * w1.y;        // conflict-free writes
        aw_t[k + 2][row] = av.z * w1.z;
        aw_t[k + 3][row] = av.w * w1.w;
        b_t[k + 0][row] = bv.x;
        b_t[k + 1][row] = bv.y;
        b_t[k + 2][row] = bv.z;
        b_t[k + 3][row] = bv.w;
    }
    ared[c0][row] = alp;
    bred[c0][row] = bep;
    __syncthreads();

    // alpha/beta partials for this K-chunk (deduplicated across tiles)
    if (jt == 0 && t < 64) {
        ws[AOFF + (s * Bn + batch) * Nn + it * 64 + t] =
            ared[0][t] + ared[1][t] + ared[2][t] + ared[3][t];
    }
    if (it == 0 && t >= 64 && t < 128) {
        const int j = t - 64;
        ws[BOFF + (s * Bn + batch) * Nn + jt * 64 + j] =
            bred[0][j] + bred[1][j] + bred[2][j] + bred[3][j];
    }

    // ---- inner: 4x4 micro-tile; per k: 2x ds_read_b128 -> 16 FMA (ratio 8)
    const int tr = t >> 4, tc = t & 15;
    float acc00 = 0.f, acc01 = 0.f, acc02 = 0.f, acc03 = 0.f;
    float acc10 = 0.f, acc11 = 0.f, acc12 = 0.f, acc13 = 0.f;
    float acc20 = 0.f, acc21 = 0.f, acc22 = 0.f, acc23 = 0.f;
    float acc30 = 0.f, acc31 = 0.f, acc32 = 0.f, acc33 = 0.f;

#pragma unroll 8
    for (int k = 0; k < KCH; ++k) {
        const float4 av = *(const float4*)&aw_t[k][4 * tr];  // 4 rows, contiguous
        const float4 bv = *(const float4*)&b_t[k][4 * tc];   // 4 cols, contiguous
        acc00 = fmaf(av.x, bv.x, acc00); acc01 = fmaf(av.x, bv.y, acc01);
        acc02 = fmaf(av.x, bv.z, acc02); acc03 = fmaf(av.x, bv.w, acc03);
        acc10 = fmaf(av.y, bv.x, acc10); acc11 = fmaf(av.y, bv.y, acc11);
        acc12 = fmaf(av.y, bv.z, acc12); acc13 = fmaf(av.y, bv.w, acc13);
        acc20 = fmaf(av.z, bv.x, acc20); acc21 = fmaf(av.z, bv.y, acc21);
        acc22 = fmaf(av.z, bv.z, acc22); acc23 = fmaf(av.z, bv.w, acc23);
        acc30 = fmaf(av.w, bv.x, acc30); acc31 = fmaf(av.w, bv.y, acc31);
        acc32 = fmaf(av.w, bv.z, acc32); acc33 = fmaf(av.w, bv.w, acc33);
    }

    float* p = ws + POFF +
               ((size_t)((s * Bn + batch) * Nn + it * 64 + 4 * tr)) * Nn +
               jt * 64 + 4 * tc;
    *(float4*)(p + 0 * Nn) = make_float4(acc00, acc01, acc02, acc03);
    *(float4*)(p + 1 * Nn) = make_float4(acc10, acc11, acc12, acc13);
    *(float4*)(p + 2 * Nn) = make_float4(acc20, acc21, acc22, acc23);
    *(float4*)(p + 3 * Nn) = make_float4(acc30, acc31, acc32, acc33);
}

// ---------------------------------------------------------------------------
// Kernel 3: out[b,i,j] = sum_s part + alpha_sum[b,i] - beta_sum[b,j] + c
// 128 blocks x 256 threads, one float4 of output per thread.
// ---------------------------------------------------------------------------
__global__ __launch_bounds__(256) void k_red(const float* __restrict__ ws,
                                             float* __restrict__ out) {
    const int idx = blockIdx.x * 256 + threadIdx.x;  // float4 index, 0..32767
    const int j4 = idx & 31;
    const int i  = (idx >> 5) & 127;
    const int b  = idx >> 12;

    float sx = 0.f, sy = 0.f, sz = 0.f, sw = 0.f, asum = 0.f;
    float bx = 0.f, by = 0.f, bz = 0.f, bw = 0.f;
#pragma unroll
    for (int s = 0; s < KS; ++s) {
        const float4 p = *(const float4*)&ws[POFF +
            ((size_t)((s * Bn + b) * Nn + i)) * Nn + 4 * j4];
        sx += p.x; sy += p.y; sz += p.z; sw += p.w;
        asum += ws[AOFF + (s * Bn + b) * Nn + i];
        const float4 bb = *(const float4*)&ws[BOFF + (s * Bn + b) * Nn + 4 * j4];
        bx += bb.x; by += bb.y; bz += bb.z; bw += bb.w;
    }
    const float c = ws[Ff];
    float4 o;
    o.x = sx + asum - bx + c;
    o.y = sy + asum - by + c;
    o.z = sz + asum - bz + c;
    o.w = sw + asum - bw + c;
    *(float4*)&out[((size_t)(b * Nn + i)) * Nn + 4 * j4] = o;
}

extern "C" void kernel_launch(void* const* d_in, const int* in_sizes, int n_in,
                              void* d_out, int out_size, void* d_ws, size_t ws_size,
                              hipStream_t stream) {
    const float* a  = (const float*)d_in[0];
    const float* b  = (const float*)d_in[1];
    const float* W1 = (const float*)d_in[2];
    const float* b1 = (const float*)d_in[3];
    const float* W2 = (const float*)d_in[4];
    const float* b2 = (const float*)d_in[5];
    float* out = (float*)d_out;
    float* ws  = (float*)d_ws;

    k_wv<<<(Ff + 1 + 3) / 4, 256, 0, stream>>>(W1, b1, W2, b2, ws);

    dim3 g2(4, Bn, KS);  // (tiles, batch, ksplit) = 256 blocks
    k_bil<<<g2, 256, 0, stream>>>(a, b, ws);

    k_red<<<128, 256, 0, stream>>>(ws, out);
}